// Round 2
// baseline (438.136 us; speedup 1.0000x reference)
//
#include <hip/hip_runtime.h>
#include <stdint.h>

#define S 1024
#define D 64
#define TQ 16
#define KT 128
#define NKT 8
#define NEG (-1e15f)
#define SCALE 0.125f

#define WB_STRIDE 1048   // bf16 elems; 2096 B row, 16B-aligned
#define QS_STRIDE 72

typedef __bf16 bf16x8 __attribute__((ext_vector_type(8)));
typedef float f32x4 __attribute__((ext_vector_type(4)));
typedef unsigned short ushort_t;

__device__ __forceinline__ unsigned short f2b(float f) {
  union { float f; uint32_t u; } c; c.f = f;
  uint32_t u = c.u;
  return (unsigned short)((u + 0x7fffu + ((u >> 16) & 1u)) >> 16);  // RNE
}
__device__ __forceinline__ float b2f(uint32_t u) {
  union { uint32_t u; float f; } c; c.u = u << 16;
  return c.f;
}

// ---- prep 1: K fp32 -> bf16, straight layout [bh][j][d] ----
__global__ __launch_bounds__(256) void prep_k_kernel(
    const float* __restrict__ Kg, ushort_t* __restrict__ Kb)
{
  const size_t idx = ((size_t)blockIdx.x * 256 + threadIdx.x) * 8;
  float4 a = *(const float4*)(Kg + idx);
  float4 b = *(const float4*)(Kg + idx + 4);
  ushort_t tmp[8];
  tmp[0]=f2b(a.x); tmp[1]=f2b(a.y); tmp[2]=f2b(a.z); tmp[3]=f2b(a.w);
  tmp[4]=f2b(b.x); tmp[5]=f2b(b.y); tmp[6]=f2b(b.z); tmp[7]=f2b(b.w);
  *(uint4*)(Kb + idx) = *(const uint4*)tmp;
}

// ---- prep 2: V fp32 [bh][j][d] -> bf16 transposed Vt [bh][d][j] ----
__global__ __launch_bounds__(256) void prep_vt_kernel(
    const float* __restrict__ Vg, ushort_t* __restrict__ Vt)
{
  __shared__ __align__(16) ushort_t lvt[D * QS_STRIDE];  // [d][j-in-tile], pad 72
  const int t = threadIdx.x;
  const int bh = blockIdx.x >> 4;
  const int j0 = (blockIdx.x & 15) << 6;

  {  // read 64j x 64d fp32, convert, scatter into lvt[d][j]
    const int j = t >> 2, sd = (t & 3) << 4;
    const float* src = Vg + ((size_t)bh * S + j0 + j) * D + sd;
#pragma unroll
    for (int c = 0; c < 4; ++c) {
      float4 f = *(const float4*)(src + (c << 2));
      lvt[(sd + (c << 2) + 0) * QS_STRIDE + j] = f2b(f.x);
      lvt[(sd + (c << 2) + 1) * QS_STRIDE + j] = f2b(f.y);
      lvt[(sd + (c << 2) + 2) * QS_STRIDE + j] = f2b(f.z);
      lvt[(sd + (c << 2) + 3) * QS_STRIDE + j] = f2b(f.w);
    }
  }
  __syncthreads();
  {  // write rows of Vt coalesced
    const int d = t >> 2, sj = (t & 3) << 4;
    ushort_t tmp[16];
#pragma unroll
    for (int c = 0; c < 4; ++c)
      *(ushort4*)&tmp[c << 2] = *(const ushort4*)&lvt[d * QS_STRIDE + sj + (c << 2)];
    ushort_t* dst = Vt + ((size_t)bh * D + d) * S + j0 + sj;
    *(uint4*)dst = *(const uint4*)&tmp[0];
    *(uint4*)(dst + 8) = *(const uint4*)&tmp[8];
  }
}

// Attention: 4096 blocks, 512 threads = 8 waves. K/Vt fragments straight from
// global (no intra-block reuse -> no LDS staging). XCD-affinity swizzle pins
// each head's 64 q-tile blocks onto one XCD so its 256 KiB K/Vt stays L2-hot.
// Depth-3 software-prefetch rings supply the MLP that VGPR=36 codegen lacked.
__global__ __launch_bounds__(512, 6) void attn_kernel(
    const float* __restrict__ Qg, const ushort_t* __restrict__ Kb,
    const ushort_t* __restrict__ Vtb, const int* __restrict__ PADg,
    float* __restrict__ OCTX, float* __restrict__ OW)
{
  __shared__ __align__(16) ushort_t wb[TQ * WB_STRIDE];   // 33536 B  scores/weights

  const int t  = threadIdx.x;
  const int w  = t >> 6;
  const int l  = t & 63;
  const int la = l & 15;
  const int lb = l >> 4;

  // HW round-robins blockIdx over 8 XCDs: XCD = blk & 7. Map so head
  // bh = (blk&7)*8 + (blk>>3)/64 -- all 64 q-tiles of a head on ONE XCD.
  const int hwblk = blockIdx.x;
  const int slot  = hwblk >> 3;
  const int bh    = ((hwblk & 7) << 3) + (slot >> 6);
  const int qt    = slot & 63;
  const int qr0   = qt << 4;

  const size_t head = (size_t)bh * S * D;
  const int* pp = PADg + (size_t)(bh >> 4) * S;   // b = bh / H

  // ---- Q A-frags direct from global: A[m=la][k=lb*8+j], two k-halves of D=64
  bf16x8 aq0, aq1;
  {
    const float* qrow = Qg + head + (size_t)(qr0 + la) * D + (lb << 3);
    float4 q00 = *(const float4*)(qrow);
    float4 q01 = *(const float4*)(qrow + 4);
    float4 q10 = *(const float4*)(qrow + 32);
    float4 q11 = *(const float4*)(qrow + 36);
    ushort_t a0[8], a1[8];
    a0[0]=f2b(q00.x); a0[1]=f2b(q00.y); a0[2]=f2b(q00.z); a0[3]=f2b(q00.w);
    a0[4]=f2b(q01.x); a0[5]=f2b(q01.y); a0[6]=f2b(q01.z); a0[7]=f2b(q01.w);
    a1[0]=f2b(q10.x); a1[1]=f2b(q10.y); a1[2]=f2b(q10.z); a1[3]=f2b(q10.w);
    a1[4]=f2b(q11.x); a1[5]=f2b(q11.y); a1[6]=f2b(q11.z); a1[7]=f2b(q11.w);
    aq0 = *(const bf16x8*)a0;
    aq1 = *(const bf16x8*)a1;
  }

  // ---- Phase 1: QK^T -> raw bf16 scores in wb. Depth-3 prefetch ring on the
  // K fragments (all ring indices compile-time after full unroll).
  {
    const ushort_t* kbase = Kb + head + (size_t)((w << 4) + la) * D + (lb << 3);
    bf16x8 k0[3], k1[3];
#define LOADK(KTI, SL) do { \
      const ushort_t* kr_ = kbase + (size_t)((KTI) * KT) * D; \
      k0[SL] = *(const bf16x8*)(kr_); \
      k1[SL] = *(const bf16x8*)(kr_ + 32); } while (0)
    LOADK(0, 0); LOADK(1, 1); LOADK(2, 2);
#pragma unroll
    for (int kt = 0; kt < NKT; ++kt) {
      const int s = kt % 3;
      bf16x8 c0 = k0[s], c1 = k1[s];      // consume slot, then refill it
      if (kt + 3 < NKT) LOADK(kt + 3, s);
      f32x4 acc = {0.f, 0.f, 0.f, 0.f};
      acc = __builtin_amdgcn_mfma_f32_16x16x32_bf16(aq0, c0, acc, 0, 0, 0);
      acc = __builtin_amdgcn_mfma_f32_16x16x32_bf16(aq1, c1, acc, 0, 0, 0);
#pragma unroll
      for (int i = 0; i < 4; ++i)         // D: row=(lb*4+i)=q, col=la=key
        wb[((lb << 2) + i) * WB_STRIDE + kt * KT + (w << 4) + la] = f2b(acc[i]);
    }
#undef LOADK
  }
  __syncthreads();

  // ---- Phase 2: fp32 softmax (2 rows per wave), in-place wb + global weights ----
#pragma unroll
  for (int rr = 0; rr < 2; ++rr) {
    const int r  = (w << 1) + rr;
    const int qr = qr0 + r;
    float lg[16];
    float m = -3.0e38f;
#pragma unroll
    for (int ii = 0; ii < 8; ++ii) {
      const int j = (l << 1) + (ii << 7);
      uint32_t pr = *(const uint32_t*)&wb[r * WB_STRIDE + j];
      int2 pv = *(const int2*)&pp[j];
      float l0 = b2f(pr & 0xffffu) * SCALE + (pv.x ? NEG : 0.0f) + ((j     > qr) ? NEG : 0.0f);
      float l1 = b2f(pr >> 16)     * SCALE + (pv.y ? NEG : 0.0f) + ((j + 1 > qr) ? NEG : 0.0f);
      lg[2 * ii] = l0; lg[2 * ii + 1] = l1;
      m = fmaxf(m, fmaxf(l0, l1));
    }
#pragma unroll
    for (int off = 32; off > 0; off >>= 1) m = fmaxf(m, __shfl_xor(m, off, 64));
    float sum = 0.f;
#pragma unroll
    for (int x = 0; x < 16; ++x) { lg[x] = __expf(lg[x] - m); sum += lg[x]; }
#pragma unroll
    for (int off = 32; off > 0; off >>= 1) sum += __shfl_xor(sum, off, 64);
    const float inv = 1.0f / sum;
    float* orow = OW + (size_t)(bh * S + qr) * S;
#pragma unroll
    for (int ii = 0; ii < 8; ++ii) {
      const int j = (l << 1) + (ii << 7);
      float w0 = lg[2 * ii] * inv, w1 = lg[2 * ii + 1] * inv;
      *(uint32_t*)&wb[r * WB_STRIDE + j] = ((uint32_t)f2b(w1) << 16) | (uint32_t)f2b(w0);
      unsigned long long uw = ((unsigned long long)__float_as_uint(w1) << 32)
                            | (unsigned long long)__float_as_uint(w0);
      __builtin_nontemporal_store(uw, (unsigned long long*)&orow[j]);  // streaming
    }
  }
  __syncthreads();

  // ---- Phase 3: PV. wave -> (d-tile = (w&3)*16, j-half = w>>2). Depth-3 ring
  // on global Vt frags, depth-2 on wb ds_reads; dual accumulator breaks the
  // 16-deep serial MFMA chain.
  const int jh = w >> 2;
  const int d0 = (w & 3) << 4;
  f32x4 cacc;
  {
    const ushort_t* vrow = Vtb + (size_t)bh * D * S + (size_t)(d0 + la) * S
                          + jh * 64 + (lb << 3);
    const ushort_t* wrow = &wb[la * WB_STRIDE + jh * 64 + (lb << 3)];
    bf16x8 vv[3], aa[2];
#define LOADV(ST, SL) do { \
      vv[SL] = *(const bf16x8*)(vrow + ((ST) >> 1) * KT + ((ST) & 1) * 32); } while (0)
#define LOADA(ST, SL) do { \
      aa[SL] = *(const bf16x8*)(wrow + ((ST) >> 1) * KT + ((ST) & 1) * 32); } while (0)
    LOADV(0, 0); LOADV(1, 1); LOADV(2, 2);
    LOADA(0, 0); LOADA(1, 1);
    f32x4 ca = {0.f, 0.f, 0.f, 0.f}, cb = {0.f, 0.f, 0.f, 0.f};
#pragma unroll
    for (int st = 0; st < 16; ++st) {
      bf16x8 av = aa[st & 1];
      bf16x8 bv = vv[st % 3];
      if (st + 2 < 16) LOADA(st + 2, st & 1);
      if (st + 3 < 16) LOADV(st + 3, st % 3);
      if (st & 1) cb = __builtin_amdgcn_mfma_f32_16x16x32_bf16(av, bv, cb, 0, 0, 0);
      else        ca = __builtin_amdgcn_mfma_f32_16x16x32_bf16(av, bv, ca, 0, 0, 0);
    }
    cacc = ca + cb;
#undef LOADV
#undef LOADA
  }
  __syncthreads();   // wb dead after this point; reuse it as the partial buffer

  // ---- Phase 4: reduce the two j-halves, store context ----
  float* pbuf = (float*)wb;                    // 4*16*20 fp32, padded (5120 B)
  if (w >= 4) {
#pragma unroll
    for (int i = 0; i < 4; ++i)
      pbuf[(w - 4) * 320 + ((lb << 2) + i) * 20 + la] = cacc[i];
  }
  __syncthreads();
  if (w < 4) {
#pragma unroll
    for (int i = 0; i < 4; ++i) {
      const int qrow = (lb << 2) + i;
      __builtin_nontemporal_store(
          cacc[i] + pbuf[w * 320 + qrow * 20 + la],
          &OCTX[((size_t)(bh * S) + qr0 + qrow) * D + d0 + la]);
    }
  }
}

extern "C" void kernel_launch(void* const* d_in, const int* in_sizes, int n_in,
                              void* d_out, int out_size, void* d_ws, size_t ws_size,
                              hipStream_t stream) {
  const float* q   = (const float*)d_in[0];
  const float* k   = (const float*)d_in[1];
  const float* v   = (const float*)d_in[2];
  const int*   pad = (const int*)d_in[3];
  // d_in[4] (look_ahead_mask) is reproduced analytically from indices.
  float* ctx  = (float*)d_out;
  float* wout = (float*)d_out + (size_t)4 * 16 * S * D;   // weights after context

  ushort_t* Kb  = (ushort_t*)d_ws;                          // 8 MB bf16 K
  ushort_t* Vtb = (ushort_t*)d_ws + (size_t)4 * 16 * S * D; // 8 MB bf16 V^T

  prep_k_kernel <<<dim3(2048), dim3(256), 0, stream>>>(k, Kb);
  prep_vt_kernel<<<dim3(1024), dim3(256), 0, stream>>>(v, Vtb);
  attn_kernel   <<<dim3(4096), dim3(512), 0, stream>>>(q, Kb, Vtb, pad, ctx, wout);
}

// Round 3
// 436.330 us; speedup vs baseline: 1.0041x; 1.0041x over previous
//
#include <hip/hip_runtime.h>
#include <stdint.h>

#define S 1024
#define D 64
#define TQ 16
#define KT 128
#define NKT 8
#define NEG (-1e15f)
#define SCALE 0.125f

#define WB_STRIDE 1048   // bf16 elems; 2096 B row, 16B-aligned
#define QS_STRIDE 72

typedef __bf16 bf16x8 __attribute__((ext_vector_type(8)));
typedef float f32x4 __attribute__((ext_vector_type(4)));
typedef unsigned short ushort_t;

__device__ __forceinline__ unsigned short f2b(float f) {
  union { float f; uint32_t u; } c; c.f = f;
  uint32_t u = c.u;
  return (unsigned short)((u + 0x7fffu + ((u >> 16) & 1u)) >> 16);  // RNE
}
__device__ __forceinline__ float b2f(uint32_t u) {
  union { uint32_t u; float f; } c; c.u = u << 16;
  return c.f;
}

// lgkm-only barrier: inter-wave handoff in attn is via LDS only, so we do NOT
// need the compiler's vmcnt(0) drain (which would stall on in-flight
// nontemporal weight stores). Rule #18: sched_barrier(0) after, so nothing is
// hoisted above the barrier.
__device__ __forceinline__ void barrier_lds_only() {
  asm volatile("s_waitcnt lgkmcnt(0)" ::: "memory");
  __builtin_amdgcn_s_barrier();
  __builtin_amdgcn_sched_barrier(0);
}

// ---- prep 1: K fp32 -> bf16, straight layout [bh][j][d] ----
__global__ __launch_bounds__(256) void prep_k_kernel(
    const float* __restrict__ Kg, ushort_t* __restrict__ Kb)
{
  const size_t idx = ((size_t)blockIdx.x * 256 + threadIdx.x) * 8;
  float4 a = *(const float4*)(Kg + idx);
  float4 b = *(const float4*)(Kg + idx + 4);
  ushort_t tmp[8];
  tmp[0]=f2b(a.x); tmp[1]=f2b(a.y); tmp[2]=f2b(a.z); tmp[3]=f2b(a.w);
  tmp[4]=f2b(b.x); tmp[5]=f2b(b.y); tmp[6]=f2b(b.z); tmp[7]=f2b(b.w);
  *(uint4*)(Kb + idx) = *(const uint4*)tmp;
}

// ---- prep 2: V fp32 [bh][j][d] -> bf16 transposed Vt [bh][d][j] ----
__global__ __launch_bounds__(256) void prep_vt_kernel(
    const float* __restrict__ Vg, ushort_t* __restrict__ Vt)
{
  __shared__ __align__(16) ushort_t lvt[D * QS_STRIDE];  // [d][j-in-tile], pad 72
  const int t = threadIdx.x;
  const int bh = blockIdx.x >> 4;
  const int j0 = (blockIdx.x & 15) << 6;

  {  // read 64j x 64d fp32, convert, scatter into lvt[d][j]
    const int j = t >> 2, sd = (t & 3) << 4;
    const float* src = Vg + ((size_t)bh * S + j0 + j) * D + sd;
#pragma unroll
    for (int c = 0; c < 4; ++c) {
      float4 f = *(const float4*)(src + (c << 2));
      lvt[(sd + (c << 2) + 0) * QS_STRIDE + j] = f2b(f.x);
      lvt[(sd + (c << 2) + 1) * QS_STRIDE + j] = f2b(f.y);
      lvt[(sd + (c << 2) + 2) * QS_STRIDE + j] = f2b(f.z);
      lvt[(sd + (c << 2) + 3) * QS_STRIDE + j] = f2b(f.w);
    }
  }
  __syncthreads();
  {  // write rows of Vt coalesced
    const int d = t >> 2, sj = (t & 3) << 4;
    ushort_t tmp[16];
#pragma unroll
    for (int c = 0; c < 4; ++c)
      *(ushort4*)&tmp[c << 2] = *(const ushort4*)&lvt[d * QS_STRIDE + sj + (c << 2)];
    ushort_t* dst = Vt + ((size_t)bh * D + d) * S + j0 + sj;
    *(uint4*)dst = *(const uint4*)&tmp[0];
    *(uint4*)(dst + 8) = *(const uint4*)&tmp[8];
  }
}

// Attention: 4096 blocks, 512 threads = 8 waves. K/Vt fragments straight from
// global (no intra-block reuse). XCD-affinity swizzle keeps each head's
// 256 KiB K/Vt on one XCD's L2 (round 2: FETCH 74->16 MB, verified).
// Round 3: pinned 16-deep load clusters (sched_barrier(0)) force MLP the
// compiler refused at VGPR=36; V cluster hoisted above softmax so its latency
// hides under VALU work; lgkm-only barriers let weight stores drain in
// parallel with PV.
__global__ __launch_bounds__(512, 4) void attn_kernel(
    const float* __restrict__ Qg, const ushort_t* __restrict__ Kb,
    const ushort_t* __restrict__ Vtb, const int* __restrict__ PADg,
    float* __restrict__ OCTX, float* __restrict__ OW)
{
  __shared__ __align__(16) ushort_t wb[TQ * WB_STRIDE];   // 33536 B  scores/weights

  const int t  = threadIdx.x;
  const int w  = t >> 6;
  const int l  = t & 63;
  const int la = l & 15;
  const int lb = l >> 4;

  // HW round-robins blockIdx over 8 XCDs: XCD = blk & 7. Map so head
  // bh = (blk&7)*8 + (blk>>3)/64 -- all 64 q-tiles of a head on ONE XCD.
  const int hwblk = blockIdx.x;
  const int slot  = hwblk >> 3;
  const int bh    = ((hwblk & 7) << 3) + (slot >> 6);
  const int qt    = slot & 63;
  const int qr0   = qt << 4;

  const size_t head = (size_t)bh * S * D;
  const int* pp = PADg + (size_t)(bh >> 4) * S;   // b = bh / H

  // ---- pad mask: same j-pattern for both softmax rows of this wave; load once
  float padf[16];
#pragma unroll
  for (int ii = 0; ii < 8; ++ii) {
    const int j = (l << 1) + (ii << 7);
    int2 pv = *(const int2*)&pp[j];
    padf[2 * ii]     = pv.x ? NEG : 0.0f;
    padf[2 * ii + 1] = pv.y ? NEG : 0.0f;
  }

  // ---- Q A-frags direct from global: A[m=la][k=lb*8+j], two k-halves of D=64
  bf16x8 aq0, aq1;
  {
    const float* qrow = Qg + head + (size_t)(qr0 + la) * D + (lb << 3);
    float4 q00 = *(const float4*)(qrow);
    float4 q01 = *(const float4*)(qrow + 4);
    float4 q10 = *(const float4*)(qrow + 32);
    float4 q11 = *(const float4*)(qrow + 36);
    ushort_t a0[8], a1[8];
    a0[0]=f2b(q00.x); a0[1]=f2b(q00.y); a0[2]=f2b(q00.z); a0[3]=f2b(q00.w);
    a0[4]=f2b(q01.x); a0[5]=f2b(q01.y); a0[6]=f2b(q01.z); a0[7]=f2b(q01.w);
    a1[0]=f2b(q10.x); a1[1]=f2b(q10.y); a1[2]=f2b(q10.z); a1[3]=f2b(q10.w);
    a1[4]=f2b(q11.x); a1[5]=f2b(q11.y); a1[6]=f2b(q11.z); a1[7]=f2b(q11.w);
    aq0 = *(const bf16x8*)a0;
    aq1 = *(const bf16x8*)a1;
  }

  // ---- Phase 1: QK^T. All 16 K-fragment loads issued up-front and PINNED
  // (sched_barrier) so 16 loads are in flight; MFMAs then retire them at
  // vmcnt(15..0) instead of one-at-a-time.
  {
    const ushort_t* kbase = Kb + head + (size_t)((w << 4) + la) * D + (lb << 3);
    bf16x8 kf[16];
#pragma unroll
    for (int st = 0; st < 16; ++st)
      kf[st] = *(const bf16x8*)(kbase + (size_t)(st >> 1) * (KT * D) + (st & 1) * 32);
    __builtin_amdgcn_sched_barrier(0);
#pragma unroll
    for (int kt = 0; kt < NKT; ++kt) {
      f32x4 acc = {0.f, 0.f, 0.f, 0.f};
      acc = __builtin_amdgcn_mfma_f32_16x16x32_bf16(aq0, kf[2 * kt],     acc, 0, 0, 0);
      acc = __builtin_amdgcn_mfma_f32_16x16x32_bf16(aq1, kf[2 * kt + 1], acc, 0, 0, 0);
#pragma unroll
      for (int i = 0; i < 4; ++i)         // D: row=(lb*4+i)=q, col=la=key
        wb[((lb << 2) + i) * WB_STRIDE + kt * KT + (w << 4) + la] = f2b(acc[i]);
    }
  }
  __syncthreads();

  // ---- Phase 2a: prefetch ALL 16 V fragments now. No inter-wave dependency;
  // issued BEFORE the weight stores so (in-order vmcnt) waiting for V never
  // waits for stores. Their latency hides under the softmax VALU below.
  const int jh = w >> 2;
  const int d0 = (w & 3) << 4;
  const ushort_t* vrow = Vtb + (size_t)bh * (D * S) + (size_t)(d0 + la) * S
                        + jh * 64 + (lb << 3);
  bf16x8 vf[16];
#pragma unroll
  for (int st = 0; st < 16; ++st)
    vf[st] = *(const bf16x8*)(vrow + (st >> 1) * KT + (st & 1) * 32);
  __builtin_amdgcn_sched_barrier(0);

  // ---- Phase 2b: fp32 softmax (2 rows per wave), in-place wb + global weights
#pragma unroll
  for (int rr = 0; rr < 2; ++rr) {
    const int r  = (w << 1) + rr;
    const int qr = qr0 + r;
    float lg[16];
    float m = -3.0e38f;
#pragma unroll
    for (int ii = 0; ii < 8; ++ii) {
      const int j = (l << 1) + (ii << 7);
      uint32_t pr = *(const uint32_t*)&wb[r * WB_STRIDE + j];
      float l0 = b2f(pr & 0xffffu) * SCALE + padf[2 * ii]     + ((j     > qr) ? NEG : 0.0f);
      float l1 = b2f(pr >> 16)     * SCALE + padf[2 * ii + 1] + ((j + 1 > qr) ? NEG : 0.0f);
      lg[2 * ii] = l0; lg[2 * ii + 1] = l1;
      m = fmaxf(m, fmaxf(l0, l1));
    }
#pragma unroll
    for (int off = 32; off > 0; off >>= 1) m = fmaxf(m, __shfl_xor(m, off, 64));
    float sum = 0.f;
#pragma unroll
    for (int x = 0; x < 16; ++x) { lg[x] = __expf(lg[x] - m); sum += lg[x]; }
#pragma unroll
    for (int off = 32; off > 0; off >>= 1) sum += __shfl_xor(sum, off, 64);
    const float inv = 1.0f / sum;
    float* orow = OW + (size_t)(bh * S + qr) * S;
#pragma unroll
    for (int ii = 0; ii < 8; ++ii) {
      const int j = (l << 1) + (ii << 7);
      float w0 = lg[2 * ii] * inv, w1 = lg[2 * ii + 1] * inv;
      *(uint32_t*)&wb[r * WB_STRIDE + j] = ((uint32_t)f2b(w1) << 16) | (uint32_t)f2b(w0);
      unsigned long long uw = ((unsigned long long)__float_as_uint(w1) << 32)
                            | (unsigned long long)__float_as_uint(w0);
      __builtin_nontemporal_store(uw, (unsigned long long*)&orow[j]);  // streaming
    }
  }
  barrier_lds_only();   // wb handoff is LDS-only; let OW stores drain under PV

  // ---- Phase 3: PV. wave -> (d-tile = (w&3)*16, j-half = w>>2). V already in
  // registers; weights stream from LDS; dual accumulator breaks the chain.
  f32x4 cacc;
  {
    const ushort_t* wrow = &wb[la * WB_STRIDE + jh * 64 + (lb << 3)];
    f32x4 ca = {0.f, 0.f, 0.f, 0.f}, cb = {0.f, 0.f, 0.f, 0.f};
#pragma unroll
    for (int st = 0; st < 16; ++st) {
      bf16x8 av = *(const bf16x8*)(wrow + (st >> 1) * KT + (st & 1) * 32);
      if (st & 1) cb = __builtin_amdgcn_mfma_f32_16x16x32_bf16(av, vf[st], cb, 0, 0, 0);
      else        ca = __builtin_amdgcn_mfma_f32_16x16x32_bf16(av, vf[st], ca, 0, 0, 0);
    }
    cacc = ca + cb;
  }
  barrier_lds_only();   // wb dead after this point; reuse it as the partial buffer

  // ---- Phase 4: reduce the two j-halves, store context ----
  float* pbuf = (float*)wb;                    // 4*16*20 fp32, padded (5120 B)
  if (w >= 4) {
#pragma unroll
    for (int i = 0; i < 4; ++i)
      pbuf[(w - 4) * 320 + ((lb << 2) + i) * 20 + la] = cacc[i];
  }
  barrier_lds_only();
  if (w < 4) {
#pragma unroll
    for (int i = 0; i < 4; ++i) {
      const int qrow = (lb << 2) + i;
      __builtin_nontemporal_store(
          cacc[i] + pbuf[w * 320 + qrow * 20 + la],
          &OCTX[((size_t)(bh * S) + qr0 + qrow) * D + d0 + la]);
    }
  }
}

extern "C" void kernel_launch(void* const* d_in, const int* in_sizes, int n_in,
                              void* d_out, int out_size, void* d_ws, size_t ws_size,
                              hipStream_t stream) {
  const float* q   = (const float*)d_in[0];
  const float* k   = (const float*)d_in[1];
  const float* v   = (const float*)d_in[2];
  const int*   pad = (const int*)d_in[3];
  // d_in[4] (look_ahead_mask) is reproduced analytically from indices.
  float* ctx  = (float*)d_out;
  float* wout = (float*)d_out + (size_t)4 * 16 * S * D;   // weights after context

  ushort_t* Kb  = (ushort_t*)d_ws;                          // 8 MB bf16 K
  ushort_t* Vtb = (ushort_t*)d_ws + (size_t)4 * 16 * S * D; // 8 MB bf16 V^T

  prep_k_kernel <<<dim3(2048), dim3(256), 0, stream>>>(k, Kb);
  prep_vt_kernel<<<dim3(1024), dim3(256), 0, stream>>>(v, Vtb);
  attn_kernel   <<<dim3(4096), dim3(512), 0, stream>>>(q, Kb, Vtb, pad, ctx, wout);
}

// Round 4
// 390.438 us; speedup vs baseline: 1.1222x; 1.1175x over previous
//
#include <hip/hip_runtime.h>
#include <stdint.h>

#define S 1024
#define D 64
#define TQ 16
#define KT 128
#define NKT 8
#define NEG (-1e15f)
#define SCALE 0.125f

#define WB_STRIDE 1048   // bf16 elems; 2096 B row, 16B-aligned
#define KB_STRIDE 72     // bf16 elems; 144 B row (16B mult)
#define VT_STRIDE 136    // bf16 elems; 272 B row (16B mult)
#define QS_STRIDE 72

typedef __bf16 bf16x8 __attribute__((ext_vector_type(8)));
typedef float f32x4 __attribute__((ext_vector_type(4)));
typedef unsigned short ushort_t;

__device__ __forceinline__ unsigned short f2b(float f) {
  union { float f; uint32_t u; } c; c.f = f;
  uint32_t u = c.u;
  return (unsigned short)((u + 0x7fffu + ((u >> 16) & 1u)) >> 16);  // RNE
}
__device__ __forceinline__ float b2f(uint32_t u) {
  union { uint32_t u; float f; } c; c.u = u << 16;
  return c.f;
}

// lgkm-only barrier: all inter-wave handoff in attn is via LDS, so we don't
// need __syncthreads()'s implicit vmcnt(0) drain (which would stall on
// in-flight nontemporal weight stores and kill the staged-load prefetch).
// Rule #18: sched_barrier(0) after, so nothing is hoisted above it.
__device__ __forceinline__ void barrier_lds_only() {
  asm volatile("s_waitcnt lgkmcnt(0)" ::: "memory");
  __builtin_amdgcn_s_barrier();
  __builtin_amdgcn_sched_barrier(0);
}

// ---- prep 1: K fp32 -> bf16, straight layout [bh][j][d] ----
__global__ __launch_bounds__(256) void prep_k_kernel(
    const float* __restrict__ Kg, ushort_t* __restrict__ Kb)
{
  const size_t idx = ((size_t)blockIdx.x * 256 + threadIdx.x) * 8;
  float4 a = *(const float4*)(Kg + idx);
  float4 b = *(const float4*)(Kg + idx + 4);
  ushort_t tmp[8];
  tmp[0]=f2b(a.x); tmp[1]=f2b(a.y); tmp[2]=f2b(a.z); tmp[3]=f2b(a.w);
  tmp[4]=f2b(b.x); tmp[5]=f2b(b.y); tmp[6]=f2b(b.z); tmp[7]=f2b(b.w);
  *(uint4*)(Kb + idx) = *(const uint4*)tmp;
}

// ---- prep 2: V fp32 [bh][j][d] -> bf16 transposed Vt [bh][d][j] ----
__global__ __launch_bounds__(256) void prep_vt_kernel(
    const float* __restrict__ Vg, ushort_t* __restrict__ Vt)
{
  __shared__ __align__(16) ushort_t lvt[D * QS_STRIDE];  // [d][j-in-tile], pad 72
  const int t = threadIdx.x;
  const int bh = blockIdx.x >> 4;
  const int j0 = (blockIdx.x & 15) << 6;

  {  // read 64j x 64d fp32, convert, scatter into lvt[d][j]
    const int j = t >> 2, sd = (t & 3) << 4;
    const float* src = Vg + ((size_t)bh * S + j0 + j) * D + sd;
#pragma unroll
    for (int c = 0; c < 4; ++c) {
      float4 f = *(const float4*)(src + (c << 2));
      lvt[(sd + (c << 2) + 0) * QS_STRIDE + j] = f2b(f.x);
      lvt[(sd + (c << 2) + 1) * QS_STRIDE + j] = f2b(f.y);
      lvt[(sd + (c << 2) + 2) * QS_STRIDE + j] = f2b(f.z);
      lvt[(sd + (c << 2) + 3) * QS_STRIDE + j] = f2b(f.w);
    }
  }
  __syncthreads();
  {  // write rows of Vt coalesced
    const int d = t >> 2, sj = (t & 3) << 4;
    ushort_t tmp[16];
#pragma unroll
    for (int c = 0; c < 4; ++c)
      *(ushort4*)&tmp[c << 2] = *(const ushort4*)&lvt[d * QS_STRIDE + sj + (c << 2)];
    ushort_t* dst = Vt + ((size_t)bh * D + d) * S + j0 + sj;
    *(uint4*)dst = *(const uint4*)&tmp[0];
    *(uint4*)(dst + 8) = *(const uint4*)&tmp[8];
  }
}

// Attention: 4096 blocks, 512 threads = 8 waves. Round-0 staged structure
// (proven fastest) + XCD head-affinity swizzle (round 2: FETCH 74->16 MB) so
// staging loads are L2-hit + software-pipelined staging (issue tile kt+1's
// global loads under tile kt's MFMA) + lgkm-only barriers + NT output stores.
__global__ __launch_bounds__(512, 6) void attn_kernel(
    const float* __restrict__ Qg, const ushort_t* __restrict__ Kb,
    const ushort_t* __restrict__ Vtb, const int* __restrict__ PADg,
    float* __restrict__ OCTX, float* __restrict__ OW)
{
  __shared__ __align__(16) ushort_t wb[TQ * WB_STRIDE];   // 33536 B  scores/weights
  __shared__ __align__(16) ushort_t ub[KT * KB_STRIDE];   // 18432 B  K/Vt tile, pbuf

  const int t  = threadIdx.x;
  const int w  = t >> 6;
  const int l  = t & 63;
  const int la = l & 15;
  const int lb = l >> 4;

  // HW round-robins blockIdx over 8 XCDs: XCD = blk & 7. Map so head
  // bh = (blk&7)*8 + (blk>>3)/64 -- all 64 q-tiles of a head on ONE XCD,
  // so its 256 KiB K/Vt is fetched from HBM once and L2-served after.
  const int hwblk = blockIdx.x;
  const int slot  = hwblk >> 3;
  const int bh    = ((hwblk & 7) << 3) + (slot >> 6);
  const int qt    = slot & 63;
  const int qr0   = qt << 4;

  const size_t head = (size_t)bh * S * D;
  const int* pp = PADg + (size_t)(bh >> 4) * S;   // b = bh / H

  // ---- Q A-frags direct from global: A[m=la][k=lb*8+j], two k-halves of D=64
  bf16x8 aq0, aq1;
  {
    const float* qrow = Qg + head + (size_t)(qr0 + la) * D + (lb << 3);
    float4 q00 = *(const float4*)(qrow);
    float4 q01 = *(const float4*)(qrow + 4);
    float4 q10 = *(const float4*)(qrow + 32);
    float4 q11 = *(const float4*)(qrow + 36);
    ushort_t a0[8], a1[8];
    a0[0]=f2b(q00.x); a0[1]=f2b(q00.y); a0[2]=f2b(q00.z); a0[3]=f2b(q00.w);
    a0[4]=f2b(q01.x); a0[5]=f2b(q01.y); a0[6]=f2b(q01.z); a0[7]=f2b(q01.w);
    a1[0]=f2b(q10.x); a1[1]=f2b(q10.y); a1[2]=f2b(q10.z); a1[3]=f2b(q10.w);
    a1[4]=f2b(q11.x); a1[5]=f2b(q11.y); a1[6]=f2b(q11.z); a1[7]=f2b(q11.w);
    aq0 = *(const bf16x8*)a0;
    aq1 = *(const bf16x8*)a1;
  }

  // ---- Phase 1: QK^T with pipelined K staging. Tile kt+1's global loads are
  // issued right after the staging barrier, so their (L2) latency hides under
  // tile kt's MFMA + score writes.
  {
    const int krow = t >> 2, koff = (t & 3) << 4;
    const ushort_t* ksrc = Kb + head + (size_t)krow * D + koff;
    ushort_t* kdst = &ub[krow * KB_STRIDE + koff];
    uint4 kra = *(const uint4*)(ksrc);
    uint4 krb = *(const uint4*)(ksrc + 8);
    for (int kt = 0; kt < NKT; ++kt) {
      *(uint4*)kdst = kra;
      *(uint4*)(kdst + 8) = krb;
      barrier_lds_only();
      if (kt + 1 < NKT) {                    // prefetch next K tile into regs
        const ushort_t* nsrc = ksrc + (size_t)(kt + 1) * (KT * D);
        kra = *(const uint4*)(nsrc);
        krb = *(const uint4*)(nsrc + 8);
      }
      const int j0 = w << 4;                 // wave owns one 16-key subtile
      f32x4 acc = {0.f, 0.f, 0.f, 0.f};
      bf16x8 b0 = *(const bf16x8*)&ub[(j0 + la) * KB_STRIDE + (lb << 3)];
      acc = __builtin_amdgcn_mfma_f32_16x16x32_bf16(aq0, b0, acc, 0, 0, 0);
      bf16x8 b1 = *(const bf16x8*)&ub[(j0 + la) * KB_STRIDE + 32 + (lb << 3)];
      acc = __builtin_amdgcn_mfma_f32_16x16x32_bf16(aq1, b1, acc, 0, 0, 0);
#pragma unroll
      for (int i = 0; i < 4; ++i)            // D: row=(lb*4+i)=q, col=la=key
        wb[((lb << 2) + i) * WB_STRIDE + kt * KT + j0 + la] = f2b(acc[i]);
      barrier_lds_only();
    }
  }

  // ---- T14 issue-early: V tile 0 global->reg loads BEFORE the softmax's
  // weight stores (in-order vmcnt: waiting for these never drains stores).
  const int vrow = t >> 3, voff = (t & 7) << 4;
  const ushort_t* vsrc = Vtb + (size_t)bh * (D * S) + (size_t)vrow * S + voff;
  uint4 vra = *(const uint4*)(vsrc);
  uint4 vrb = *(const uint4*)(vsrc + 8);

  // ---- Phase 2: fp32 softmax (2 rows per wave), in-place wb + global weights
#pragma unroll
  for (int rr = 0; rr < 2; ++rr) {
    const int r  = (w << 1) + rr;
    const int qr = qr0 + r;
    float lg[16];
    float m = -3.0e38f;
#pragma unroll
    for (int ii = 0; ii < 8; ++ii) {
      const int j = (l << 1) + (ii << 7);
      uint32_t pr = *(const uint32_t*)&wb[r * WB_STRIDE + j];
      int2 pv = *(const int2*)&pp[j];
      float l0 = b2f(pr & 0xffffu) * SCALE + (pv.x ? NEG : 0.0f) + ((j     > qr) ? NEG : 0.0f);
      float l1 = b2f(pr >> 16)     * SCALE + (pv.y ? NEG : 0.0f) + ((j + 1 > qr) ? NEG : 0.0f);
      lg[2 * ii] = l0; lg[2 * ii + 1] = l1;
      m = fmaxf(m, fmaxf(l0, l1));
    }
#pragma unroll
    for (int off = 32; off > 0; off >>= 1) m = fmaxf(m, __shfl_xor(m, off, 64));
    float sum = 0.f;
#pragma unroll
    for (int x = 0; x < 16; ++x) { lg[x] = __expf(lg[x] - m); sum += lg[x]; }
#pragma unroll
    for (int off = 32; off > 0; off >>= 1) sum += __shfl_xor(sum, off, 64);
    const float inv = 1.0f / sum;
    float* orow = OW + (size_t)(bh * S + qr) * S;
#pragma unroll
    for (int ii = 0; ii < 8; ++ii) {
      const int j = (l << 1) + (ii << 7);
      float w0 = lg[2 * ii] * inv, w1 = lg[2 * ii + 1] * inv;
      *(uint32_t*)&wb[r * WB_STRIDE + j] = ((uint32_t)f2b(w1) << 16) | (uint32_t)f2b(w0);
      unsigned long long uw = ((unsigned long long)__float_as_uint(w1) << 32)
                            | (unsigned long long)__float_as_uint(w0);
      __builtin_nontemporal_store(uw, (unsigned long long*)&orow[j]);  // streaming
    }
  }
  barrier_lds_only();   // wb handoff is LDS-only; OW stores keep draining

  // ---- Phase 3: PV with pipelined Vt staging. wave -> (d-tile=(w&3)*16,
  // j-half=w>>2); tile kt+1's loads issue under tile kt's MFMA.
  const int jh = w >> 2;
  const int d0 = (w & 3) << 4;
  ushort_t* vdst = &ub[vrow * VT_STRIDE + voff];
  f32x4 cacc = {0.f, 0.f, 0.f, 0.f};
  for (int kt = 0; kt < NKT; ++kt) {
    *(uint4*)vdst = vra;
    *(uint4*)(vdst + 8) = vrb;
    barrier_lds_only();
    if (kt + 1 < NKT) {                      // prefetch next Vt tile into regs
      const ushort_t* nv = vsrc + (kt + 1) * KT;
      vra = *(const uint4*)(nv);
      vrb = *(const uint4*)(nv + 8);
    }
#pragma unroll
    for (int ks = 0; ks < 2; ++ks) {
      const int jt = jh * 64 + ks * 32;
      bf16x8 af = *(const bf16x8*)&wb[la * WB_STRIDE + kt * KT + jt + (lb << 3)];
      bf16x8 bf = *(const bf16x8*)&ub[(d0 + la) * VT_STRIDE + jt + (lb << 3)];
      cacc = __builtin_amdgcn_mfma_f32_16x16x32_bf16(af, bf, cacc, 0, 0, 0);
    }
    barrier_lds_only();
  }

  // ---- Phase 4: reduce the two j-halves, store context ----
  float* pbuf = (float*)ub;                    // 4*16*20 fp32, padded (5120 B)
  if (w >= 4) {
#pragma unroll
    for (int i = 0; i < 4; ++i)
      pbuf[(w - 4) * 320 + ((lb << 2) + i) * 20 + la] = cacc[i];
  }
  barrier_lds_only();
  if (w < 4) {
#pragma unroll
    for (int i = 0; i < 4; ++i) {
      const int qrow = (lb << 2) + i;
      __builtin_nontemporal_store(
          cacc[i] + pbuf[w * 320 + qrow * 20 + la],
          &OCTX[((size_t)(bh * S) + qr0 + qrow) * D + d0 + la]);
    }
  }
}

extern "C" void kernel_launch(void* const* d_in, const int* in_sizes, int n_in,
                              void* d_out, int out_size, void* d_ws, size_t ws_size,
                              hipStream_t stream) {
  const float* q   = (const float*)d_in[0];
  const float* k   = (const float*)d_in[1];
  const float* v   = (const float*)d_in[2];
  const int*   pad = (const int*)d_in[3];
  // d_in[4] (look_ahead_mask) is reproduced analytically from indices.
  float* ctx  = (float*)d_out;
  float* wout = (float*)d_out + (size_t)4 * 16 * S * D;   // weights after context

  ushort_t* Kb  = (ushort_t*)d_ws;                          // 8 MB bf16 K
  ushort_t* Vtb = (ushort_t*)d_ws + (size_t)4 * 16 * S * D; // 8 MB bf16 V^T

  prep_k_kernel <<<dim3(2048), dim3(256), 0, stream>>>(k, Kb);
  prep_vt_kernel<<<dim3(1024), dim3(256), 0, stream>>>(v, Vtb);
  attn_kernel   <<<dim3(4096), dim3(512), 0, stream>>>(q, Kb, Vtb, pad, ctx, wout);
}

// Round 5
// 380.313 us; speedup vs baseline: 1.1520x; 1.0266x over previous
//
#include <hip/hip_runtime.h>
#include <stdint.h>

#define S 1024
#define D 64
#define TQ 16
#define KT 128
#define NKT 8
#define NEG (-1e15f)
#define SCALE 0.125f

#define WB_STRIDE 1048   // bf16 elems; 2096 B row, 16B-aligned
#define KB_STRIDE 72     // bf16 elems; 144 B row (16B mult)
#define VT_STRIDE 136    // bf16 elems; 272 B row (16B mult)
#define QS_STRIDE 72

typedef __bf16 bf16x8 __attribute__((ext_vector_type(8)));
typedef float f32x4 __attribute__((ext_vector_type(4)));
typedef unsigned short ushort_t;

__device__ __forceinline__ unsigned short f2b(float f) {
  union { float f; uint32_t u; } c; c.f = f;
  uint32_t u = c.u;
  return (unsigned short)((u + 0x7fffu + ((u >> 16) & 1u)) >> 16);  // RNE
}
__device__ __forceinline__ float b2f(uint32_t u) {
  union { uint32_t u; float f; } c; c.u = u << 16;
  return c.f;
}

// lgkm-only barrier: all inter-wave handoff in attn is via LDS, so we don't
// need __syncthreads()'s implicit vmcnt(0) drain (which would stall on
// in-flight nontemporal weight stores). Rule #18: sched_barrier(0) after.
__device__ __forceinline__ void barrier_lds_only() {
  asm volatile("s_waitcnt lgkmcnt(0)" ::: "memory");
  __builtin_amdgcn_s_barrier();
  __builtin_amdgcn_sched_barrier(0);
}

// ---- prep 1: K fp32 -> bf16, straight layout [bh][j][d] ----
__global__ __launch_bounds__(256) void prep_k_kernel(
    const float* __restrict__ Kg, ushort_t* __restrict__ Kb)
{
  const size_t idx = ((size_t)blockIdx.x * 256 + threadIdx.x) * 8;
  float4 a = *(const float4*)(Kg + idx);
  float4 b = *(const float4*)(Kg + idx + 4);
  ushort_t tmp[8];
  tmp[0]=f2b(a.x); tmp[1]=f2b(a.y); tmp[2]=f2b(a.z); tmp[3]=f2b(a.w);
  tmp[4]=f2b(b.x); tmp[5]=f2b(b.y); tmp[6]=f2b(b.z); tmp[7]=f2b(b.w);
  *(uint4*)(Kb + idx) = *(const uint4*)tmp;
}

// ---- prep 2: V fp32 [bh][j][d] -> bf16 transposed Vt [bh][d][j] ----
__global__ __launch_bounds__(256) void prep_vt_kernel(
    const float* __restrict__ Vg, ushort_t* __restrict__ Vt)
{
  __shared__ __align__(16) ushort_t lvt[D * QS_STRIDE];  // [d][j-in-tile], pad 72
  const int t = threadIdx.x;
  const int bh = blockIdx.x >> 4;
  const int j0 = (blockIdx.x & 15) << 6;

  {  // read 64j x 64d fp32, convert, scatter into lvt[d][j]
    const int j = t >> 2, sd = (t & 3) << 4;
    const float* src = Vg + ((size_t)bh * S + j0 + j) * D + sd;
#pragma unroll
    for (int c = 0; c < 4; ++c) {
      float4 f = *(const float4*)(src + (c << 2));
      lvt[(sd + (c << 2) + 0) * QS_STRIDE + j] = f2b(f.x);
      lvt[(sd + (c << 2) + 1) * QS_STRIDE + j] = f2b(f.y);
      lvt[(sd + (c << 2) + 2) * QS_STRIDE + j] = f2b(f.z);
      lvt[(sd + (c << 2) + 3) * QS_STRIDE + j] = f2b(f.w);
    }
  }
  __syncthreads();
  {  // write rows of Vt coalesced
    const int d = t >> 2, sj = (t & 3) << 4;
    ushort_t tmp[16];
#pragma unroll
    for (int c = 0; c < 4; ++c)
      *(ushort4*)&tmp[c << 2] = *(const ushort4*)&lvt[d * QS_STRIDE + sj + (c << 2)];
    ushort_t* dst = Vt + ((size_t)bh * D + d) * S + j0 + sj;
    *(uint4*)dst = *(const uint4*)&tmp[0];
    *(uint4*)(dst + 8) = *(const uint4*)&tmp[8];
  }
}

// Attention: 4096 blocks, 512 threads = 8 waves.
// Round 5: WAVE-PRIVATE staging. In both staged loops each wave consumes
// exactly the bytes it can stage itself (ph1: K rows w*16..+15; ph3: the
// (d0,jh) 16x64 chunk). Staging regions are disjoint per wave and per-wave
// DS ops are in-order, so the 32 in-loop barriers vanish (35 -> 4 total).
// Depth-2 register prefetch ring covers L2 latency. Retained from earlier
// rounds (all verified): XCD head-affinity swizzle (FETCH 74->16 MB),
// lgkm-only barriers (don't drain NT weight stores), NT output stores.
__global__ __launch_bounds__(512, 6) void attn_kernel(
    const float* __restrict__ Qg, const ushort_t* __restrict__ Kb,
    const ushort_t* __restrict__ Vtb, const int* __restrict__ PADg,
    float* __restrict__ OCTX, float* __restrict__ OW)
{
  __shared__ __align__(16) ushort_t wb[TQ * WB_STRIDE];   // 33536 B  scores/weights
  __shared__ __align__(16) ushort_t ub[KT * KB_STRIDE];   // 18432 B  K/Vt tiles, pbuf

  const int t  = threadIdx.x;
  const int w  = t >> 6;
  const int l  = t & 63;
  const int la = l & 15;
  const int lb = l >> 4;

  // HW round-robins blockIdx over 8 XCDs: XCD = blk & 7. Map so head
  // bh = (blk&7)*8 + (blk>>3)/64 -- all 64 q-tiles of a head on ONE XCD,
  // so its 256 KiB K/Vt is fetched from HBM once and L2-served after.
  const int hwblk = blockIdx.x;
  const int slot  = hwblk >> 3;
  const int bh    = ((hwblk & 7) << 3) + (slot >> 6);
  const int qt    = slot & 63;
  const int qr0   = qt << 4;

  const size_t head = (size_t)bh * S * D;
  const int* pp = PADg + (size_t)(bh >> 4) * S;   // b = bh / H

  // ---- Q A-frags direct from global: A[m=la][k=lb*8+j], two k-halves of D=64
  bf16x8 aq0, aq1;
  {
    const float* qrow = Qg + head + (size_t)(qr0 + la) * D + (lb << 3);
    float4 q00 = *(const float4*)(qrow);
    float4 q01 = *(const float4*)(qrow + 4);
    float4 q10 = *(const float4*)(qrow + 32);
    float4 q11 = *(const float4*)(qrow + 36);
    ushort_t a0[8], a1[8];
    a0[0]=f2b(q00.x); a0[1]=f2b(q00.y); a0[2]=f2b(q00.z); a0[3]=f2b(q00.w);
    a0[4]=f2b(q01.x); a0[5]=f2b(q01.y); a0[6]=f2b(q01.z); a0[7]=f2b(q01.w);
    a1[0]=f2b(q10.x); a1[1]=f2b(q10.y); a1[2]=f2b(q10.z); a1[3]=f2b(q10.w);
    a1[4]=f2b(q11.x); a1[5]=f2b(q11.y); a1[6]=f2b(q11.z); a1[7]=f2b(q11.w);
    aq0 = *(const bf16x8*)a0;
    aq1 = *(const bf16x8*)a1;
  }

  // ---- Phase 1: QK^T, wave-private K staging, zero barriers.
  // Wave w stages K rows w*16..+15 of each tile (2 KB, 32 B/lane coalesced)
  // into its own ub slice and reads only that slice. Per-wave DS ordering
  // makes RAW (write->frag read) and WAR (frag read->next write) safe.
  {
    const int kr = l >> 2;                 // row within wave's 16
    const int ko = (l & 3) << 4;           // 0/16/32/48 ushorts
    const int rowg = (w << 4) + kr;        // row within the 128-key tile
    const ushort_t* ksrc = Kb + head + (size_t)rowg * D + ko;
    ushort_t* kdst = &ub[rowg * KB_STRIDE + ko];
    const int j0 = w << 4;
    uint4 kra[2], krb[2];
    kra[0] = *(const uint4*)(ksrc);
    krb[0] = *(const uint4*)(ksrc + 8);
    kra[1] = *(const uint4*)(ksrc + (size_t)(KT * D));
    krb[1] = *(const uint4*)(ksrc + (size_t)(KT * D) + 8);
#pragma unroll
    for (int kt = 0; kt < NKT; ++kt) {
      *(uint4*)kdst = kra[kt & 1];
      *(uint4*)(kdst + 8) = krb[kt & 1];
      if (kt + 2 < NKT) {                  // depth-2 prefetch ring
        const ushort_t* ns = ksrc + (size_t)(kt + 2) * (KT * D);
        kra[kt & 1] = *(const uint4*)(ns);
        krb[kt & 1] = *(const uint4*)(ns + 8);
      }
      f32x4 acc = {0.f, 0.f, 0.f, 0.f};
      bf16x8 b0 = *(const bf16x8*)&ub[(j0 + la) * KB_STRIDE + (lb << 3)];
      acc = __builtin_amdgcn_mfma_f32_16x16x32_bf16(aq0, b0, acc, 0, 0, 0);
      bf16x8 b1 = *(const bf16x8*)&ub[(j0 + la) * KB_STRIDE + 32 + (lb << 3)];
      acc = __builtin_amdgcn_mfma_f32_16x16x32_bf16(aq1, b1, acc, 0, 0, 0);
#pragma unroll
      for (int i = 0; i < 4; ++i)          // D: row=(lb*4+i)=q, col=la=key
        wb[((lb << 2) + i) * WB_STRIDE + kt * KT + j0 + la] = f2b(acc[i]);
    }
  }
  barrier_lds_only();   // publish wb scores to all waves

  // ---- T14 issue-early: V tiles 0 and 1 (wave-private 16d x 64j chunks)
  // loaded to regs BEFORE the softmax's weight stores; latency hides under
  // softmax VALU, and in-order vmcnt means waiting for them never waits on
  // the NT stores issued after.
  const int jh = w >> 2;
  const int d0 = (w & 3) << 4;
  const int vr = l >> 2;                   // d-row within wave's 16
  const int vo = (l & 3) << 4;             // 0/16/32/48 ushorts within 64-j half
  const ushort_t* vsrc = Vtb + (size_t)bh * (D * S) + (size_t)(d0 + vr) * S
                        + jh * 64 + vo;
  ushort_t* vdst = &ub[(d0 + vr) * VT_STRIDE + jh * 64 + vo];
  uint4 vra[2], vrb[2];
  vra[0] = *(const uint4*)(vsrc);
  vrb[0] = *(const uint4*)(vsrc + 8);
  vra[1] = *(const uint4*)(vsrc + KT);
  vrb[1] = *(const uint4*)(vsrc + KT + 8);

  // ---- Phase 2: fp32 softmax (2 rows per wave), in-place wb + global weights
#pragma unroll
  for (int rr = 0; rr < 2; ++rr) {
    const int r  = (w << 1) + rr;
    const int qr = qr0 + r;
    float lg[16];
    float m = -3.0e38f;
#pragma unroll
    for (int ii = 0; ii < 8; ++ii) {
      const int j = (l << 1) + (ii << 7);
      uint32_t pr = *(const uint32_t*)&wb[r * WB_STRIDE + j];
      int2 pv = *(const int2*)&pp[j];
      float l0 = b2f(pr & 0xffffu) * SCALE + (pv.x ? NEG : 0.0f) + ((j     > qr) ? NEG : 0.0f);
      float l1 = b2f(pr >> 16)     * SCALE + (pv.y ? NEG : 0.0f) + ((j + 1 > qr) ? NEG : 0.0f);
      lg[2 * ii] = l0; lg[2 * ii + 1] = l1;
      m = fmaxf(m, fmaxf(l0, l1));
    }
#pragma unroll
    for (int off = 32; off > 0; off >>= 1) m = fmaxf(m, __shfl_xor(m, off, 64));
    float sum = 0.f;
#pragma unroll
    for (int x = 0; x < 16; ++x) { lg[x] = __expf(lg[x] - m); sum += lg[x]; }
#pragma unroll
    for (int off = 32; off > 0; off >>= 1) sum += __shfl_xor(sum, off, 64);
    const float inv = 1.0f / sum;
    float* orow = OW + (size_t)(bh * S + qr) * S;
#pragma unroll
    for (int ii = 0; ii < 8; ++ii) {
      const int j = (l << 1) + (ii << 7);
      float w0 = lg[2 * ii] * inv, w1 = lg[2 * ii + 1] * inv;
      *(uint32_t*)&wb[r * WB_STRIDE + j] = ((uint32_t)f2b(w1) << 16) | (uint32_t)f2b(w0);
      unsigned long long uw = ((unsigned long long)__float_as_uint(w1) << 32)
                            | (unsigned long long)__float_as_uint(w0);
      __builtin_nontemporal_store(uw, (unsigned long long*)&orow[j]);  // streaming
    }
  }
  barrier_lds_only();   // publish bf16 weights in wb; OW stores keep draining

  // ---- Phase 3: PV, wave-private Vt staging, zero barriers.
  // Wave w stages its 16d x 64j chunk of each Vt tile into its own ub region;
  // reads (d0+la)*VT_STRIDE + jh*64.. stay within that region.
  f32x4 cacc = {0.f, 0.f, 0.f, 0.f};
  {
#pragma unroll
    for (int kt = 0; kt < NKT; ++kt) {
      *(uint4*)vdst = vra[kt & 1];
      *(uint4*)(vdst + 8) = vrb[kt & 1];
      if (kt + 2 < NKT) {                  // depth-2 prefetch ring
        const ushort_t* nv = vsrc + (kt + 2) * KT;
        vra[kt & 1] = *(const uint4*)(nv);
        vrb[kt & 1] = *(const uint4*)(nv + 8);
      }
#pragma unroll
      for (int ks = 0; ks < 2; ++ks) {
        const int jt = jh * 64 + ks * 32;
        bf16x8 af = *(const bf16x8*)&wb[la * WB_STRIDE + kt * KT + jt + (lb << 3)];
        bf16x8 bf = *(const bf16x8*)&ub[(d0 + la) * VT_STRIDE + jt + (lb << 3)];
        cacc = __builtin_amdgcn_mfma_f32_16x16x32_bf16(af, bf, cacc, 0, 0, 0);
      }
    }
  }
  barrier_lds_only();   // ub dead for staging; reuse as the partial buffer

  // ---- Phase 4: reduce the two j-halves, store context ----
  float* pbuf = (float*)ub;                    // 4*16*20 fp32, padded (5120 B)
  if (w >= 4) {
#pragma unroll
    for (int i = 0; i < 4; ++i)
      pbuf[(w - 4) * 320 + ((lb << 2) + i) * 20 + la] = cacc[i];
  }
  barrier_lds_only();
  if (w < 4) {
#pragma unroll
    for (int i = 0; i < 4; ++i) {
      const int qrow = (lb << 2) + i;
      __builtin_nontemporal_store(
          cacc[i] + pbuf[w * 320 + qrow * 20 + la],
          &OCTX[((size_t)(bh * S) + qr0 + qrow) * D + d0 + la]);
    }
  }
}

extern "C" void kernel_launch(void* const* d_in, const int* in_sizes, int n_in,
                              void* d_out, int out_size, void* d_ws, size_t ws_size,
                              hipStream_t stream) {
  const float* q   = (const float*)d_in[0];
  const float* k   = (const float*)d_in[1];
  const float* v   = (const float*)d_in[2];
  const int*   pad = (const int*)d_in[3];
  // d_in[4] (look_ahead_mask) is reproduced analytically from indices.
  float* ctx  = (float*)d_out;
  float* wout = (float*)d_out + (size_t)4 * 16 * S * D;   // weights after context

  ushort_t* Kb  = (ushort_t*)d_ws;                          // 8 MB bf16 K
  ushort_t* Vtb = (ushort_t*)d_ws + (size_t)4 * 16 * S * D; // 8 MB bf16 V^T

  prep_k_kernel <<<dim3(2048), dim3(256), 0, stream>>>(k, Kb);
  prep_vt_kernel<<<dim3(1024), dim3(256), 0, stream>>>(v, Vtb);
  attn_kernel   <<<dim3(4096), dim3(512), 0, stream>>>(q, Kb, Vtb, pad, ctx, wout);
}